// Round 18
// baseline (105.253 us; speedup 1.0000x reference)
//
#include <hip/hip_runtime.h>
#include <cmath>

#define B_ 4
#define S_ 4096
#define D_ 1024
#define H_ 128
#define M_ (B_*S_)   // 16384 total rows

typedef _Float16 half8 __attribute__((ext_vector_type(8)));
typedef _Float16 half4 __attribute__((ext_vector_type(4)));
typedef float f32x4 __attribute__((ext_vector_type(4)));
typedef float f32x16 __attribute__((ext_vector_type(16)));
typedef int i32x4 __attribute__((ext_vector_type(4)));

#define LOG2E 1.44269504088896340f

// async global->LDS, 16B per lane; LDS dest is wave-uniform base + lane*16
__device__ __forceinline__ void gload16(const void* g, void* l) {
    __builtin_amdgcn_global_load_lds(
        (const __attribute__((address_space(1))) unsigned int*)g,
        (__attribute__((address_space(3))) unsigned int*)l,
        16, 0, 0);
}

// ---------------------------------------------------------------------------
// Kernel 0: convert Wq/Wk/Wv (fp32) -> wh fp16 [3][H][D]  (order q,k,v)
// ---------------------------------------------------------------------------
__global__ __launch_bounds__(256) void conv_w(
    const float* __restrict__ Wq, const float* __restrict__ Wk,
    const float* __restrict__ Wv, _Float16* __restrict__ wh)
{
    const int idx  = blockIdx.x * 256 + threadIdx.x;
    const int base = idx * 8;                       // < 3*H*D = 393216
    const int m    = base >> 17;                    // H*D = 131072
    const int off  = base & ((H_ * D_) - 1);
    const float* src = (m == 0 ? Wq : m == 1 ? Wk : Wv) + off;
    const float4 a = ((const float4*)src)[0];
    const float4 c = ((const float4*)src)[1];
    half8 h = { (_Float16)a.x, (_Float16)a.y, (_Float16)a.z, (_Float16)a.w,
                (_Float16)c.x, (_Float16)c.y, (_Float16)c.z, (_Float16)c.w };
    *(half8*)(wh + base) = h;
}

// ---------------------------------------------------------------------------
// Kernel 1: QKV projection (R16-proven: 4 blocks/CU, single-buffered W).
// grid = (M/64, 3): y=0 -> q (scaled by log2e/sqrt(H)), y=1 -> k, y=2 -> v^T
// ---------------------------------------------------------------------------
__global__ __launch_bounds__(256, 4) void proj_kernel(
    const float* __restrict__ x, const _Float16* __restrict__ wh,
    const float* __restrict__ bq, const float* __restrict__ bk,
    const float* __restrict__ bv,
    _Float16* __restrict__ qh, _Float16* __restrict__ kh,
    _Float16* __restrict__ vt)
{
    __shared__ _Float16 Xs[2][64][72];   // +8 pad (reg-staged writes)
    __shared__ _Float16 Ws2[128][64];    // single buffer; swizzled content

    const int t = threadIdx.x;
    const int yb = blockIdx.y;
    const float* __restrict__ bias = (yb == 0) ? bq : (yb == 1) ? bk : bv;
    const int m0 = blockIdx.x * 64;
    const int w = t >> 6, lane = t & 63;
    const int lg = lane >> 4, lr = lane & 15;

    f32x4 acc[8];
    #pragma unroll
    for (int i = 0; i < 8; ++i) acc[i] = f32x4{0.f, 0.f, 0.f, 0.f};

    const int xrow = t >> 2, xc = (t & 3) * 16;
    const float* xbase = x + (size_t)(m0 + xrow) * D_ + xc;

    int wbyte[4];
    #pragma unroll
    for (int i = 0; i < 4; ++i) {
        const int wrow = 32 * w + 8 * i + (lane >> 3);
        const int wblk = (lane & 7) ^ (lane >> 3);
        wbyte[i] = (wrow * D_ + wblk * 8) * 2;
    }
    const char* whb = (const char*)(wh + (size_t)yb * H_ * D_);

    float4 xfA[4], xfB[4];

#define WISSUE(KT)                                                            \
    {                                                                         \
        const char* wsrc = whb + (KT) * (64 * 2);                             \
        _Pragma("unroll")                                                     \
        for (int i = 0; i < 4; ++i)                                           \
            gload16(wsrc + wbyte[i], &Ws2[32 * w + 8 * i][0]);                \
    }
#define XISSUE(KT, XS)                                                        \
    {                                                                         \
        const float4* xs_ = (const float4*)(xbase + (KT) * 64);               \
        _Pragma("unroll") for (int i = 0; i < 4; ++i) XS[i] = xs_[i];         \
    }
#define XWRITE(XS, BUF)                                                       \
    {                                                                         \
        _Pragma("unroll") for (int i = 0; i < 4; ++i) {                       \
            half4 h = { (_Float16)XS[i].x, (_Float16)XS[i].y,                 \
                        (_Float16)XS[i].z, (_Float16)XS[i].w };               \
            *(half4*)&Xs[BUF][xrow][xc + 4 * i] = h;                          \
        }                                                                     \
    }
#define PMFMA(BUF)                                                            \
    {                                                                         \
        _Pragma("unroll") for (int kk = 0; kk < 2; ++kk) {                    \
            half8 a = *(const half8*)&Xs[BUF][w * 16 + lr][kk * 32 + 8 * lg]; \
            _Pragma("unroll") for (int ni = 0; ni < 8; ++ni) {                \
                half8 bfr = *(const half8*)&Ws2[ni * 16 + lr]                 \
                                [((4 * kk + lg) ^ (lr & 7)) * 8];             \
                acc[ni] = __builtin_amdgcn_mfma_f32_16x16x32_f16(a, bfr, acc[ni], 0, 0, 0); \
            }                                                                 \
        }                                                                     \
    }

    XISSUE(0, xfA)
    XISSUE(1, xfB)
    XWRITE(xfA, 0)
    WISSUE(0)
    __syncthreads();

    for (int kt = 0; kt < 16; kt += 2) {
        PMFMA(0)
        XWRITE(xfB, 1)
        if (kt + 2 < 16) XISSUE(kt + 2, xfA)
        __syncthreads();
        WISSUE(kt + 1)
        __syncthreads();
        PMFMA(1)
        if (kt + 2 < 16) {
            XWRITE(xfA, 0)
            if (kt + 3 < 16) XISSUE(kt + 3, xfB)
            __syncthreads();
            WISSUE(kt + 2)
            __syncthreads();
        }
    }
#undef WISSUE
#undef XISSUE
#undef XWRITE
#undef PMFMA

    const float qscale = 0.08838834764831845f * LOG2E;
    const int rowb = m0 + w * 16 + lg * 4;
    #pragma unroll
    for (int ni = 0; ni < 8; ++ni) {
        const int col = ni * 16 + lr;
        const float bval = bias[col];
        if (yb == 0) {
            #pragma unroll
            for (int r = 0; r < 4; ++r)
                qh[(size_t)(rowb + r) * H_ + col] = (_Float16)((acc[ni][r] + bval) * qscale);
        } else if (yb == 1) {
            #pragma unroll
            for (int r = 0; r < 4; ++r)
                kh[(size_t)(rowb + r) * H_ + col] = (_Float16)(acc[ni][r] + bval);
        } else {
            const int bb = rowb >> 12, s0 = rowb & (S_ - 1);
            half4 h;
            #pragma unroll
            for (int r = 0; r < 4; ++r) h[r] = (_Float16)(acc[ni][r] + bval);
            *(half4*)&vt[(size_t)bb * H_ * S_ + (size_t)col * S_ + s0] = h;
        }
    }
}

// ---------------------------------------------------------------------------
// Kernel 2: flash attention, WAVE-INDEPENDENT: block = 32 q-rows; each wave
// owns a private kv quarter (S/4) with PRIVATE LDS buffers. Zero block
// barriers in the MAIN LOOP (wave-local lgkmcnt/vmcnt only). Two barriers
// at the end: (1) all waves done reading u.s BEFORE the accL overlay is
// written (union overlap — R17's NaN was this race), (2) overlay visible
// before merge reads. Math = R9-verified 32x32 core at kv-tile = 32.
// ---------------------------------------------------------------------------
struct KvBufs { _Float16 K[4][32][128]; _Float16 V[4][128][32]; };  // 64 KB
union AttnU {
    KvBufs s;
    float accL[4][64][65];   // merge overlay, 65-stride (conflict-free)
};

__device__ __forceinline__ void attn_tile32s(
    const _Float16 (&Kb)[32][128], const _Float16 (&Vb)[128][32],
    const half8 (&qf)[8], f32x16 (&acc2)[4], float& m_, float& l_,
    int muse, int lane)
{
    const unsigned long long bz = __ballot(muse == 0);
    const int l31 = lane & 31, hi = lane >> 5;
    const int l7 = l31 & 7, l3 = l31 & 3;

    // S^T = K Q^T : sf[r] = S'[kv = (r&3)+8*(r>>2)+4hi][q = l31], kv in 0..31
    f32x16 sf;
    #pragma unroll
    for (int r = 0; r < 16; ++r) sf[r] = 0.f;
    #pragma unroll
    for (int kt = 0; kt < 8; ++kt) {
        half8 kb = *(const half8*)&Kb[l31][((2 * kt + hi) ^ l7) * 8];
        sf = __builtin_amdgcn_mfma_f32_32x32x16_f16(kb, qf[kt], sf, 0, 0, 0);
    }
    if (bz) {   // padding mask (reference: where(mask==0, -1e9))
        #pragma unroll
        for (int r = 0; r < 16; ++r) {
            const int kv = (r & 3) + 8 * (r >> 2) + 4 * hi;
            if ((bz >> kv) & 1ull) sf[r] = -3e9f;
        }
    }
    // online softmax in exp2 domain: one q-row per lane, ONE shuffle
    float tmax = sf[0];
    #pragma unroll
    for (int r = 1; r < 16; ++r) tmax = fmaxf(tmax, sf[r]);
    tmax = fmaxf(tmax, __shfl_xor(tmax, 32));
    if (!__all(tmax <= m_ + 8.f)) {   // defer-max
        const float mn  = fmaxf(m_, tmax);
        const float scl = exp2f(m_ - mn);
        m_ = mn; l_ *= scl;
        #pragma unroll
        for (int hb = 0; hb < 4; ++hb) acc2[hb] *= scl;
    }
    float rsum = 0.f;
    #pragma unroll
    for (int r = 0; r < 16; ++r) {
        const float p = exp2f(sf[r] - m_);
        sf[r] = p;
        rsum += p;
    }
    rsum += __shfl_xor(rsum, 32);
    l_ += rsum;

    // pack: pkw[i] holds fp16 pair kv = {8*(i>>1)+4hi+2*(i&1), +1}
    int pkw[8];
    #pragma unroll
    for (int i = 0; i < 8; ++i) {
        auto h2 = __builtin_amdgcn_cvt_pkrtz(sf[2 * i], sf[2 * i + 1]);
        pkw[i] = __builtin_bit_cast(int, h2);
    }
    // exchange: chunk s words on half hi: n0,n1 from lo-half's (4s, 4s+1)... 
    // derived identically to the R9-verified pattern with hf -> s.
    i32x4 pbi[2];
    #pragma unroll
    for (int s = 0; s < 2; ++s) {
        const int i0 = 4 * s;
        const int sA = hi ? pkw[i0 + 0] : pkw[i0 + 2];
        const int sB = hi ? pkw[i0 + 1] : pkw[i0 + 3];
        const int rA = __shfl_xor(sA, 32);
        const int rB = __shfl_xor(sB, 32);
        pbi[s][0] = hi ? rA : pkw[i0 + 0];
        pbi[s][1] = hi ? rB : pkw[i0 + 1];
        pbi[s][2] = hi ? pkw[i0 + 2] : rA;
        pbi[s][3] = hi ? pkw[i0 + 3] : rB;
    }
    // O^T += V^T P^T : acc2[hb][r] = O[q=l31][h = 32hb + (r&3)+8*(r>>2)+4hi]
    #pragma unroll
    for (int s = 0; s < 2; ++s) {
        const half8 pb = __builtin_bit_cast(half8, pbi[s]);
        #pragma unroll
        for (int hb = 0; hb < 4; ++hb) {
            half8 vb = *(const half8*)&Vb[hb * 32 + l31][((2 * s + hi) ^ l3) * 8];
            acc2[hb] = __builtin_amdgcn_mfma_f32_32x32x16_f16(vb, pb, acc2[hb], 0, 0, 0);
        }
    }
}

__global__ __launch_bounds__(256, 2) void attn_kernel(
    const _Float16* __restrict__ qh, const _Float16* __restrict__ kh,
    const _Float16* __restrict__ vt, const int* __restrict__ mask,
    float* __restrict__ out)
{
    __shared__ AttnU u;
    __shared__ float mlm[4][64], mll[4][64];

    const int t = threadIdx.x;
    const int id = blockIdx.x;                 // 512 blocks
    // XCD-locality: XCD x = id&7 serves batch b = x>>1 (K/V 2MB fits L2)
    const int xx = id & 7;
    const int b  = xx >> 1;
    const int qt = (xx & 1) * 64 + (id >> 3);  // 0..127
    const int q0 = qt * 32;
    const int w = t >> 6, lane = t & 63;
    const int l31 = lane & 31, hi = lane >> 5;
    const int kvw0 = w * (S_ / 4);             // wave-private kv quarter
    const int iters = (S_ / 4) / 32;           // 32 tiles of 32 kv

    // wave-private staging offsets (swizzled global source, linear LDS dest)
    int kbyte[8], vbyte[8];
    #pragma unroll
    for (int i = 0; i < 8; ++i) {
        const int krow = 4 * i + (lane >> 4);          // kv row 0..31
        const int kblk = (lane & 15) ^ (krow & 7);     // 16 blocks/row
        kbyte[i] = (krow * H_ + kblk * 8) * 2;
        const int vrow = 16 * i + (lane >> 2);         // h row 0..127
        const int vblk = (lane & 3) ^ (vrow & 3);      // 4 blocks/row
        vbyte[i] = (vrow * S_ + vblk * 8) * 2;
    }
    const char* kbase_b = (const char*)(kh + (size_t)(b * S_ + kvw0) * H_);
    const char* vbase_b = (const char*)(vt + (size_t)b * H_ * S_ + kvw0);
    const int*  mbase   = mask + b * S_ + kvw0 + l31;

#define ISSUE_TILE(IT)                                                        \
    {                                                                         \
        const char* kb_t = kbase_b + (size_t)(IT) * (32 * H_ * 2);            \
        const char* vb_t = vbase_b + (size_t)(IT) * (32 * 2);                 \
        _Pragma("unroll")                                                     \
        for (int i = 0; i < 8; ++i)                                           \
            gload16(kb_t + kbyte[i], &u.s.K[w][4 * i][0]);                    \
        _Pragma("unroll")                                                     \
        for (int i = 0; i < 8; ++i)                                           \
            gload16(vb_t + vbyte[i], &u.s.V[w][16 * i][0]);                   \
    }
#define WLGKM asm volatile("s_waitcnt lgkmcnt(0)" ::: "memory")
#define WVM   asm volatile("s_waitcnt vmcnt(0)"   ::: "memory")

    // Q fragments: lane owns q-row (q0 + l31), SAME for all 4 waves
    half8 qf[8];
    {
        const _Float16* qp = qh + (size_t)(b * S_ + q0 + l31) * H_ + 8 * hi;
        #pragma unroll
        for (int kt = 0; kt < 8; ++kt) qf[kt] = *(const half8*)(qp + 16 * kt);
    }

    float m_ = -1e30f, l_ = 0.f;
    f32x16 acc2[4];
    #pragma unroll
    for (int hb = 0; hb < 4; ++hb)
        #pragma unroll
        for (int r = 0; r < 16; ++r) acc2[hb][r] = 0.f;

    // wave-local pipeline: no block barriers in this loop
    ISSUE_TILE(0)
    int mreg = mbase[0];
    WVM;
    for (int it = 0; it < iters; ++it) {
        attn_tile32s(u.s.K[w], u.s.V[w], qf, acc2, m_, l_, mreg, lane);
        if (it + 1 < iters) {
            WLGKM;                 // wave's ds_reads of this tile returned
            ISSUE_TILE(it + 1)     // overwrite own buffers
            mreg = mbase[(it + 1) * 32];
            WVM;                   // loads landed (covered by other waves' work)
        }
    }
#undef ISSUE_TILE
#undef WLGKM
#undef WVM

    // ---- merge the 4 kv-quarter partials ----
    __syncthreads();   // ALL waves done reading u.s before overlay write (R17 fix)
    mlm[w][lane] = m_;
    mll[w][lane] = l_;
    #pragma unroll
    for (int hb = 0; hb < 4; ++hb)
        #pragma unroll
        for (int r = 0; r < 16; ++r)
            u.accL[w][lane][hb * 16 + r] = acc2[hb][r];
    __syncthreads();   // overlay visible to all

    // thread (w, lane) merges value block hb = w for its lane's q-row
    float M = mlm[0][lane];
    #pragma unroll
    for (int wp = 1; wp < 4; ++wp) M = fmaxf(M, mlm[wp][lane]);
    float sc[4], Z = 0.f;
    #pragma unroll
    for (int wp = 0; wp < 4; ++wp) {
        sc[wp] = exp2f(mlm[wp][lane] - M);
        Z += sc[wp] * mll[wp][lane];
    }
    const float inv = 1.f / Z;
    float* op = out + (size_t)(b * S_ + q0 + l31) * H_;
    #pragma unroll
    for (int i = 0; i < 8; ++i) {          // pairs (r=2i, 2i+1): h, h+1
        const int r0 = 2 * i;
        float v0 = 0.f, v1 = 0.f;
        #pragma unroll
        for (int wp = 0; wp < 4; ++wp) {
            v0 += sc[wp] * u.accL[wp][lane][w * 16 + r0];
            v1 += sc[wp] * u.accL[wp][lane][w * 16 + r0 + 1];
        }
        const int h = 32 * w + 2 * (i & 1) + 8 * (i >> 1) + 4 * hi;
        float2 v2 = make_float2(v0 * inv, v1 * inv);
        *(float2*)(op + h) = v2;
    }
}

// ---------------------------------------------------------------------------
extern "C" void kernel_launch(void* const* d_in, const int* in_sizes, int n_in,
                              void* d_out, int out_size, void* d_ws, size_t ws_size,
                              hipStream_t stream)
{
    (void)in_sizes; (void)n_in; (void)out_size; (void)ws_size;
    // setup_inputs order: inputs, Wk, bk, Wq, bq, Wv, bv, padding_mask
    const float* x  = (const float*)d_in[0];
    const float* Wk = (const float*)d_in[1];
    const float* bk = (const float*)d_in[2];
    const float* Wq = (const float*)d_in[3];
    const float* bq = (const float*)d_in[4];
    const float* Wv = (const float*)d_in[5];
    const float* bv = (const float*)d_in[6];
    const int* mask = (const int*)d_in[7];

    char* ws = (char*)d_ws;
    const size_t qkvBytes = (size_t)M_ * H_ * sizeof(_Float16);   // 4 MB each
    _Float16* qh = (_Float16*)ws;
    _Float16* kh = (_Float16*)(ws + qkvBytes);
    _Float16* vt = (_Float16*)(ws + 2 * qkvBytes);                // [B][H][S]
    _Float16* wh = (_Float16*)(ws + 3 * qkvBytes);                // [3][H][D]

    conv_w<<<dim3(3 * H_ * D_ / (256 * 8)), 256, 0, stream>>>(Wq, Wk, Wv, wh);
    proj_kernel<<<dim3(M_ / 64, 3), 256, 0, stream>>>(x, wh, bq, bk, bv, qh, kh, vt);
    attn_kernel<<<dim3(512), 256, 0, stream>>>(qh, kh, vt, mask, (float*)d_out);
}

// Round 19
// 103.008 us; speedup vs baseline: 1.0218x; 1.0218x over previous
//
#include <hip/hip_runtime.h>
#include <cmath>

#define B_ 4
#define S_ 4096
#define D_ 1024
#define H_ 128
#define M_ (B_*S_)   // 16384 total rows
#define NQT 32       // S / 128 q-tiles (attn QBLK = 128)

typedef _Float16 half8 __attribute__((ext_vector_type(8)));
typedef _Float16 half4 __attribute__((ext_vector_type(4)));
typedef float f32x4 __attribute__((ext_vector_type(4)));
typedef float f32x16 __attribute__((ext_vector_type(16)));
typedef int i32x4 __attribute__((ext_vector_type(4)));

#define LOG2E 1.44269504088896340f

// async global->LDS, 16B per lane; LDS dest is wave-uniform base + lane*16
__device__ __forceinline__ void gload16(const void* g, void* l) {
    __builtin_amdgcn_global_load_lds(
        (const __attribute__((address_space(1))) unsigned int*)g,
        (__attribute__((address_space(3))) unsigned int*)l,
        16, 0, 0);
}

// ---------------------------------------------------------------------------
// Kernel 0: convert Wq/Wk/Wv (fp32) -> wh fp16 [3][H][D]  (order q,k,v)
// ---------------------------------------------------------------------------
__global__ __launch_bounds__(256) void conv_w(
    const float* __restrict__ Wq, const float* __restrict__ Wk,
    const float* __restrict__ Wv, _Float16* __restrict__ wh)
{
    const int idx  = blockIdx.x * 256 + threadIdx.x;
    const int base = idx * 8;                       // < 3*H*D = 393216
    const int m    = base >> 17;                    // H*D = 131072
    const int off  = base & ((H_ * D_) - 1);
    const float* src = (m == 0 ? Wq : m == 1 ? Wk : Wv) + off;
    const float4 a = ((const float4*)src)[0];
    const float4 c = ((const float4*)src)[1];
    half8 h = { (_Float16)a.x, (_Float16)a.y, (_Float16)a.z, (_Float16)a.w,
                (_Float16)c.x, (_Float16)c.y, (_Float16)c.z, (_Float16)c.w };
    *(half8*)(wh + base) = h;
}

// ---------------------------------------------------------------------------
// Kernel 1: QKV projection (R16-proven: 4 blocks/CU, single-buffered W).
// grid = (M/64, 3): y=0 -> q (scaled by log2e/sqrt(H)), y=1 -> k, y=2 -> v^T
// ---------------------------------------------------------------------------
__global__ __launch_bounds__(256, 4) void proj_kernel(
    const float* __restrict__ x, const _Float16* __restrict__ wh,
    const float* __restrict__ bq, const float* __restrict__ bk,
    const float* __restrict__ bv,
    _Float16* __restrict__ qh, _Float16* __restrict__ kh,
    _Float16* __restrict__ vt)
{
    __shared__ _Float16 Xs[2][64][72];   // +8 pad (reg-staged writes)
    __shared__ _Float16 Ws2[128][64];    // single buffer; swizzled content

    const int t = threadIdx.x;
    const int yb = blockIdx.y;
    const float* __restrict__ bias = (yb == 0) ? bq : (yb == 1) ? bk : bv;
    const int m0 = blockIdx.x * 64;
    const int w = t >> 6, lane = t & 63;
    const int lg = lane >> 4, lr = lane & 15;

    f32x4 acc[8];
    #pragma unroll
    for (int i = 0; i < 8; ++i) acc[i] = f32x4{0.f, 0.f, 0.f, 0.f};

    const int xrow = t >> 2, xc = (t & 3) * 16;
    const float* xbase = x + (size_t)(m0 + xrow) * D_ + xc;

    int wbyte[4];
    #pragma unroll
    for (int i = 0; i < 4; ++i) {
        const int wrow = 32 * w + 8 * i + (lane >> 3);
        const int wblk = (lane & 7) ^ (lane >> 3);
        wbyte[i] = (wrow * D_ + wblk * 8) * 2;
    }
    const char* whb = (const char*)(wh + (size_t)yb * H_ * D_);

    float4 xfA[4], xfB[4];

#define WISSUE(KT)                                                            \
    {                                                                         \
        const char* wsrc = whb + (KT) * (64 * 2);                             \
        _Pragma("unroll")                                                     \
        for (int i = 0; i < 4; ++i)                                           \
            gload16(wsrc + wbyte[i], &Ws2[32 * w + 8 * i][0]);                \
    }
#define XISSUE(KT, XS)                                                        \
    {                                                                         \
        const float4* xs_ = (const float4*)(xbase + (KT) * 64);               \
        _Pragma("unroll") for (int i = 0; i < 4; ++i) XS[i] = xs_[i];         \
    }
#define XWRITE(XS, BUF)                                                       \
    {                                                                         \
        _Pragma("unroll") for (int i = 0; i < 4; ++i) {                       \
            half4 h = { (_Float16)XS[i].x, (_Float16)XS[i].y,                 \
                        (_Float16)XS[i].z, (_Float16)XS[i].w };               \
            *(half4*)&Xs[BUF][xrow][xc + 4 * i] = h;                          \
        }                                                                     \
    }
#define PMFMA(BUF)                                                            \
    {                                                                         \
        _Pragma("unroll") for (int kk = 0; kk < 2; ++kk) {                    \
            half8 a = *(const half8*)&Xs[BUF][w * 16 + lr][kk * 32 + 8 * lg]; \
            _Pragma("unroll") for (int ni = 0; ni < 8; ++ni) {                \
                half8 bfr = *(const half8*)&Ws2[ni * 16 + lr]                 \
                                [((4 * kk + lg) ^ (lr & 7)) * 8];             \
                acc[ni] = __builtin_amdgcn_mfma_f32_16x16x32_f16(a, bfr, acc[ni], 0, 0, 0); \
            }                                                                 \
        }                                                                     \
    }

    XISSUE(0, xfA)
    XISSUE(1, xfB)
    XWRITE(xfA, 0)
    WISSUE(0)
    __syncthreads();

    for (int kt = 0; kt < 16; kt += 2) {
        PMFMA(0)
        XWRITE(xfB, 1)
        if (kt + 2 < 16) XISSUE(kt + 2, xfA)
        __syncthreads();
        WISSUE(kt + 1)
        __syncthreads();
        PMFMA(1)
        if (kt + 2 < 16) {
            XWRITE(xfA, 0)
            if (kt + 3 < 16) XISSUE(kt + 3, xfB)
            __syncthreads();
            WISSUE(kt + 2)
            __syncthreads();
        }
    }
#undef WISSUE
#undef XISSUE
#undef XWRITE
#undef PMFMA

    const float qscale = 0.08838834764831845f * LOG2E;
    const int rowb = m0 + w * 16 + lg * 4;
    #pragma unroll
    for (int ni = 0; ni < 8; ++ni) {
        const int col = ni * 16 + lr;
        const float bval = bias[col];
        if (yb == 0) {
            #pragma unroll
            for (int r = 0; r < 4; ++r)
                qh[(size_t)(rowb + r) * H_ + col] = (_Float16)((acc[ni][r] + bval) * qscale);
        } else if (yb == 1) {
            #pragma unroll
            for (int r = 0; r < 4; ++r)
                kh[(size_t)(rowb + r) * H_ + col] = (_Float16)(acc[ni][r] + bval);
        } else {
            const int bb = rowb >> 12, s0 = rowb & (S_ - 1);
            half4 h;
            #pragma unroll
            for (int r = 0; r < 4; ++r) h[r] = (_Float16)(acc[ni][r] + bval);
            *(half4*)&vt[(size_t)bb * H_ * S_ + (size_t)col * S_ + s0] = h;
        }
    }
}

// ---------------------------------------------------------------------------
// Kernel 2: flash attention, 32x32x16 MFMA core — best-measured variant
// (R9/R15/R16: attn ~77-78 us). Swapped operands (lane owns one q-row),
// exp2 softmax, defer-max, shfl_xor P-exchange, pre-swizzled-source gload16,
// ping-pong double buffer, ONE __syncthreads per tile.
// C/D map (m74/m101): col = lane&31, row = (r&3) + 8*(r>>2) + 4*(lane>>5).
// ---------------------------------------------------------------------------
__device__ __forceinline__ void attn_tile32(
    const _Float16 (&Kb)[64][128], const _Float16 (&Vb)[128][64],
    const half8 (&qf)[8], f32x16 (&acc2)[4], float& m_, float& l_,
    int muse, int lane)
{
    const unsigned long long bz = __ballot(muse == 0);
    const int l31 = lane & 31, l7 = lane & 7, hi = lane >> 5;

    // S^T = K Q^T : sf[nb][r] = S'[kv = 32nb + (r&3)+8*(r>>2)+4hi][q = l31]
    f32x16 sf[2];
    #pragma unroll
    for (int nb = 0; nb < 2; ++nb)
        #pragma unroll
        for (int r = 0; r < 16; ++r) sf[nb][r] = 0.f;
    #pragma unroll
    for (int kt = 0; kt < 8; ++kt) {
        #pragma unroll
        for (int nb = 0; nb < 2; ++nb) {
            half8 kb = *(const half8*)&Kb[nb * 32 + l31][((2 * kt + hi) ^ l7) * 8];
            sf[nb] = __builtin_amdgcn_mfma_f32_32x32x16_f16(kb, qf[kt], sf[nb], 0, 0, 0);
        }
    }
    if (bz) {   // padding mask (reference: where(mask==0, -1e9))
        #pragma unroll
        for (int nb = 0; nb < 2; ++nb)
            #pragma unroll
            for (int r = 0; r < 16; ++r) {
                const int kv = nb * 32 + (r & 3) + 8 * (r >> 2) + 4 * hi;
                if ((bz >> kv) & 1ull) sf[nb][r] = -3e9f;
            }
    }
    // online softmax in exp2 domain: one q-row per lane, ONE shuffle
    float tmax = sf[0][0];
    #pragma unroll
    for (int nb = 0; nb < 2; ++nb)
        #pragma unroll
        for (int r = 0; r < 16; ++r) tmax = fmaxf(tmax, sf[nb][r]);
    tmax = fmaxf(tmax, __shfl_xor(tmax, 32));
    if (!__all(tmax <= m_ + 8.f)) {   // defer-max: skip rescale when safe
        const float mn  = fmaxf(m_, tmax);
        const float scl = exp2f(m_ - mn);
        m_ = mn; l_ *= scl;
        #pragma unroll
        for (int hb = 0; hb < 4; ++hb) acc2[hb] *= scl;
    }
    float rsum = 0.f;
    #pragma unroll
    for (int nb = 0; nb < 2; ++nb)
        #pragma unroll
        for (int r = 0; r < 16; ++r) {
            const float p = exp2f(sf[nb][r] - m_);
            sf[nb][r] = p;
            rsum += p;
        }
    rsum += __shfl_xor(rsum, 32);
    l_ += rsum;

    // pack P pairs: pkw[nb][i] holds kv = 32nb + 8*(i>>1) + 4hi + 2*(i&1), +1
    int pkw[2][8];
    #pragma unroll
    for (int nb = 0; nb < 2; ++nb)
        #pragma unroll
        for (int i = 0; i < 8; ++i) {
            auto h2 = __builtin_amdgcn_cvt_pkrtz(sf[nb][2 * i], sf[nb][2 * i + 1]);
            pkw[nb][i] = __builtin_bit_cast(int, h2);
        }
    // exchange across lane halves (direction-unambiguous shfl_xor):
    // lo lanes keep w0,w1 and receive other-half's w0,w1 as w2,w3;
    // hi lanes keep w2,w3 and receive other-half's w2,w3 as w0,w1.
    #pragma unroll
    for (int nb = 0; nb < 2; ++nb)
        #pragma unroll
        for (int hf = 0; hf < 2; ++hf) {
            const int i0 = hf * 4;
            const int sA = hi ? pkw[nb][i0 + 0] : pkw[nb][i0 + 2];
            const int sB = hi ? pkw[nb][i0 + 1] : pkw[nb][i0 + 3];
            const int rA = __shfl_xor(sA, 32);   // lo<-hi's w0 ; hi<-lo's w2
            const int rB = __shfl_xor(sB, 32);   // lo<-hi's w1 ; hi<-lo's w3
            const int n0 = hi ? rA : pkw[nb][i0 + 0];
            const int n1 = hi ? rB : pkw[nb][i0 + 1];
            const int n2 = hi ? pkw[nb][i0 + 2] : rA;
            const int n3 = hi ? pkw[nb][i0 + 3] : rB;
            pkw[nb][i0 + 0] = n0; pkw[nb][i0 + 1] = n1;
            pkw[nb][i0 + 2] = n2; pkw[nb][i0 + 3] = n3;
        }
    // O^T += V^T P^T : acc2[hb][r] = O[q=l31][h = 32hb + (r&3)+8*(r>>2)+4hi]
    #pragma unroll
    for (int s = 0; s < 4; ++s) {
        const int nb = s >> 1, hf = s & 1;
        const half8 pb = __builtin_bit_cast(half8,
            i32x4{ pkw[nb][hf * 4 + 0], pkw[nb][hf * 4 + 1],
                   pkw[nb][hf * 4 + 2], pkw[nb][hf * 4 + 3] });
        #pragma unroll
        for (int hb = 0; hb < 4; ++hb) {
            half8 vb = *(const half8*)&Vb[hb * 32 + l31][((2 * s + hi) ^ l7) * 8];
            acc2[hb] = __builtin_amdgcn_mfma_f32_32x32x16_f16(vb, pb, acc2[hb], 0, 0, 0);
        }
    }
}

__global__ __launch_bounds__(256, 2) void attn_kernel(
    const _Float16* __restrict__ qh, const _Float16* __restrict__ kh,
    const _Float16* __restrict__ vt, const int* __restrict__ mask,
    float* __restrict__ pout, float* __restrict__ pm, float* __restrict__ pl,
    const int nsplit)
{
    __shared__ _Float16 Ks[2][64][128];   // [buf][kv][d]; content swizzled
    __shared__ _Float16 Vs[2][128][64];   // [buf][h][kv]

    const int t = threadIdx.x;
    const int id = blockIdx.x;
    // L2-locality swizzle: each XCD owns ncombo/8 (b,split) combos.
    int qt, sp, b;
    const int ncombo = B_ * nsplit;
    if ((ncombo & 7) == 0) {
        const int per_xcd = ncombo >> 3;
        const int j = id >> 3;
        qt = j & (NQT - 1);
        const int combo = (id & 7) * per_xcd + (j >> 5);   // log2(NQT)=5
        sp = combo % nsplit; b = combo / nsplit;
    } else {
        qt = id & (NQT - 1);
        const int rest = id >> 5;
        sp = rest % nsplit; b = rest / nsplit;
    }
    const int q0 = qt * 128;
    const int w = t >> 6, lane = t & 63;
    const int l31 = lane & 31, hi = lane >> 5;
    const int kvlen  = S_ / nsplit;
    const int iters  = kvlen >> 6;
    const int kvbase = sp * kvlen;

    // per-lane byte offsets of the SWIZZLED global source (loop-invariant)
    int kbyte[4], vbyte[4];
    #pragma unroll
    for (int i = 0; i < 4; ++i) {
        const int krow = 16 * w + 4 * i + (lane >> 4);
        const int kblk = (lane & 15) ^ (krow & 7);
        kbyte[i] = (krow * H_ + kblk * 8) * 2;
        const int vrow = 32 * w + 8 * i + (lane >> 3);
        const int vblk = (lane & 7) ^ (lane >> 3);   // vrow&7 == lane>>3
        vbyte[i] = (vrow * S_ + vblk * 8) * 2;
    }
    const char* kbase_b = (const char*)(kh + (size_t)(b * S_ + kvbase) * H_);
    const char* vbase_b = (const char*)(vt + (size_t)b * H_ * S_ + kvbase);
    const char* mbase_b = (const char*)(mask + b * S_ + kvbase + lane);

#define ISSUE_TILE(IT, NB)                                                    \
    {                                                                         \
        const char* kb_t = kbase_b + (size_t)(IT) * (64 * H_ * 2);            \
        const char* vb_t = vbase_b + (size_t)(IT) * (64 * 2);                 \
        _Pragma("unroll")                                                     \
        for (int i = 0; i < 4; ++i)                                           \
            gload16(kb_t + kbyte[i], &Ks[NB][16 * w + 4 * i][0]);             \
        _Pragma("unroll")                                                     \
        for (int i = 0; i < 4; ++i)                                           \
            gload16(vb_t + vbyte[i], &Vs[NB][32 * w + 8 * i][0]);             \
    }

    // Q fragments: lane owns q-row (q0 + 32w + l31); d = 16kt + 8hi + j
    half8 qf[8];
    {
        const _Float16* qp = qh + (size_t)(b * S_ + q0 + 32 * w + l31) * H_ + 8 * hi;
        #pragma unroll
        for (int kt = 0; kt < 8; ++kt) qf[kt] = *(const half8*)(qp + 16 * kt);
    }

    float m_ = -1e30f, l_ = 0.f;
    f32x16 acc2[4];
    #pragma unroll
    for (int hb = 0; hb < 4; ++hb)
        #pragma unroll
        for (int r = 0; r < 16; ++r) acc2[hb][r] = 0.f;

    ISSUE_TILE(0, 0)
    int mA = *(const int*)mbase_b;
    int mB = 0;
    __syncthreads();   // tile 0 staged

    for (int it = 0; it < iters; it += 2) {
        // ---- tile it (buf 0); prefetch it+1 flies during this compute ----
        if (it + 1 < iters) {
            ISSUE_TILE(it + 1, 1)
            mB = *(const int*)(mbase_b + (size_t)(it + 1) * 256);
        }
        attn_tile32(Ks[0], Vs[0], qf, acc2, m_, l_, mA, lane);
        __syncthreads();
        // ---- tile it+1 (buf 1); prefetch it+2 flies during this compute ----
        if (it + 2 < iters) {
            ISSUE_TILE(it + 2, 0)
            mA = *(const int*)(mbase_b + (size_t)(it + 2) * 256);
        }
        if (it + 1 < iters)
            attn_tile32(Ks[1], Vs[1], qf, acc2, m_, l_, mB, lane);
        __syncthreads();
    }
#undef ISSUE_TILE

    // store unnormalized partials: lane writes its q-row, 64 h-values
    const int qrow = b * S_ + q0 + 32 * w + l31;
    float* op = pout + (size_t)(sp * M_ + qrow) * H_;
    #pragma unroll
    for (int hb = 0; hb < 4; ++hb)
        #pragma unroll
        for (int i = 0; i < 8; ++i) {
            const int h = hb * 32 + 2 * (i & 1) + 8 * (i >> 1) + 4 * hi;
            float2 v2 = make_float2(acc2[hb][2 * i], acc2[hb][2 * i + 1]);
            *(float2*)(op + h) = v2;
        }
    if (hi == 0) {
        pm[sp * M_ + qrow] = m_;
        pl[sp * M_ + qrow] = l_;
    }
}

// ---------------------------------------------------------------------------
// Kernel 3: combine KV-split partials and normalize (exp2 domain).
// Vectorized: each thread handles 4 h-values (f32x4 loads/stores).
// ---------------------------------------------------------------------------
__global__ __launch_bounds__(256) void combine_kernel(
    const float* __restrict__ pout, const float* __restrict__ pm,
    const float* __restrict__ pl, float* __restrict__ out, const int nsplit)
{
    const int idx = blockIdx.x * 256 + threadIdx.x;   // < M_*H_/4
    const int row = idx >> 5;          // global row (32 f32x4 per row)
    const int c4  = (idx & 31) * 4;
    float M = -1e30f;
    for (int sp = 0; sp < nsplit; ++sp) M = fmaxf(M, pm[sp * M_ + row]);
    float Z = 0.f;
    f32x4 o = f32x4{0.f, 0.f, 0.f, 0.f};
    for (int sp = 0; sp < nsplit; ++sp) {
        const float wgt = exp2f(pm[sp * M_ + row] - M);
        Z += wgt * pl[sp * M_ + row];
        const f32x4 p = *(const f32x4*)&pout[(size_t)(sp * M_ + row) * H_ + c4];
        o += wgt * p;
    }
    const float inv = 1.f / Z;
    *(f32x4*)&out[(size_t)row * H_ + c4] = o * inv;
}

// ---------------------------------------------------------------------------
extern "C" void kernel_launch(void* const* d_in, const int* in_sizes, int n_in,
                              void* d_out, int out_size, void* d_ws, size_t ws_size,
                              hipStream_t stream)
{
    (void)in_sizes; (void)n_in; (void)out_size;
    // setup_inputs order: inputs, Wk, bk, Wq, bq, Wv, bv, padding_mask
    const float* x  = (const float*)d_in[0];
    const float* Wk = (const float*)d_in[1];
    const float* bk = (const float*)d_in[2];
    const float* Wq = (const float*)d_in[3];
    const float* bq = (const float*)d_in[4];
    const float* Wv = (const float*)d_in[5];
    const float* bv = (const float*)d_in[6];
    const int* mask = (const int*)d_in[7];

    char* ws = (char*)d_ws;
    const size_t qkvBytes = (size_t)M_ * H_ * sizeof(_Float16);   // 4 MB each
    _Float16* qh = (_Float16*)ws;
    _Float16* kh = (_Float16*)(ws + qkvBytes);
    _Float16* vt = (_Float16*)(ws + 2 * qkvBytes);                // [B][H][S]
    _Float16* wh = (_Float16*)(ws + 3 * qkvBytes);                // [3][H][D]
    const size_t whBytes = (size_t)3 * H_ * D_ * sizeof(_Float16);
    char* rest = ws + 3 * qkvBytes + whBytes;

    int nsplit = 4;   // best-measured: 512 blocks = 2/CU, 46 MB partials
    const size_t perSplit = (size_t)M_ * H_ * 4 + 2 * (size_t)M_ * 4;
    while (nsplit > 1 &&
           3 * qkvBytes + whBytes + (size_t)nsplit * perSplit > ws_size) nsplit >>= 1;

    float* pout = (float*)rest;
    float* pm   = (float*)(rest + (size_t)nsplit * M_ * H_ * 4);
    float* pl   = pm + (size_t)nsplit * M_;

    conv_w<<<dim3(3 * H_ * D_ / (256 * 8)), 256, 0, stream>>>(Wq, Wk, Wv, wh);
    proj_kernel<<<dim3(M_ / 64, 3), 256, 0, stream>>>(x, wh, bq, bk, bv, qh, kh, vt);
    attn_kernel<<<dim3(NQT * B_ * nsplit), 256, 0, stream>>>(qh, kh, vt, mask, pout, pm, pl, nsplit);
    combine_kernel<<<dim3(M_ * H_ / (256 * 4)), 256, 0, stream>>>(pout, pm, pl, (float*)d_out, nsplit);
}